// Round 3
// baseline (507.576 us; speedup 1.0000x reference)
//
#include <hip/hip_runtime.h>

#define MDIM 512
#define NDIM 8192
#define KDIM 8192
#define BM 128
#define BN 128
#define BK 64

typedef short v8s __attribute__((ext_vector_type(8)));
typedef float v4f __attribute__((ext_vector_type(4)));
typedef int   v4i __attribute__((ext_vector_type(4)));

// pack two f32 into two bf16 by truncation (high halves) via byte-perm
__device__ __forceinline__ unsigned pack_bf2(float a, float b) {
  unsigned ia = __builtin_bit_cast(unsigned, a);
  unsigned ib = __builtin_bit_cast(unsigned, b);
  return __builtin_amdgcn_perm(ib, ia, 0x07060302u);  // lo16=a.hi, hi16=b.hi
}

// round-to-nearest-ish (+0x8000 before truncation); inputs finite
__device__ __forceinline__ unsigned pack_bf2_rnd(float a, float b) {
  unsigned ia = __builtin_bit_cast(unsigned, a) + 0x8000u;
  unsigned ib = __builtin_bit_cast(unsigned, b) + 0x8000u;
  return __builtin_amdgcn_perm(ib, ia, 0x07060302u);
}

// Raw barrier WITHOUT vmcnt drain: in-flight global loads stay outstanding
// across it (the whole point). lgkmcnt(0) publishes our ds_writes; fences
// stop IR/sched motion across the barrier (rule 18).
__device__ __forceinline__ void block_sync() {
  asm volatile("s_waitcnt lgkmcnt(0)" ::: "memory");
  __builtin_amdgcn_sched_barrier(0);
  __builtin_amdgcn_s_barrier();
  __builtin_amdgcn_sched_barrier(0);
  asm volatile("" ::: "memory");
}

// x fp32 -> bf16, tiled [4 mt][128 ktg][1024 units]*8elem, unit position
// pos = (u&3)*256 + (u>>2) so the gemm's 4 per-thread loads are each
// lane-dense (16B * 64 lanes contiguous). u: row=u>>3 (0..127), q=u&7.
__global__ __launch_bounds__(256) void cvt_x_kernel(const float* __restrict__ x,
                                                    short* __restrict__ xb) {
  const int g = blockIdx.x * 256 + threadIdx.x;  // global unit position
  const int mt = g >> 17;
  const int rem = g & 131071;
  const int ktg = rem >> 10;
  const int upos = rem & 1023;
  const int u = (upos & 255) * 4 + (upos >> 8);  // invert pos()
  const int row = u >> 3;
  const int q = u & 7;
  const float* src = x + (size_t)(mt * BM + row) * KDIM + ktg * BK + q * 8;
  v4f f0 = *(const v4f*)src;
  v4f f1 = *(const v4f*)(src + 4);
  v4i o;
  o[0] = pack_bf2_rnd(f0[0], f0[1]);
  o[1] = pack_bf2_rnd(f0[2], f0[3]);
  o[2] = pack_bf2_rnd(f1[0], f1[1]);
  o[3] = pack_bf2_rnd(f1[2], f1[3]);
  *(v4i*)(xb + (size_t)g * 8) = o;
}

// out[i] = p0[i] + p1[i]  (split-K reduction, deterministic)
__global__ __launch_bounds__(256) void reduce_kernel(const float* __restrict__ p,
                                                     float* __restrict__ out) {
  const size_t i = ((size_t)blockIdx.x * 256 + threadIdx.x) * 4;
  v4f a = *(const v4f*)(p + i);
  v4f b = *(const v4f*)(p + (size_t)MDIM * NDIM + i);
  *(v4f*)(out + i) = a + b;
}

// Fused dequant GEMM, depth-2 register pipeline + raw barriers.
// SPLIT: 2-way split-K (grid 512, partials), else grid 256 direct.
template <bool SPLIT>
__global__ __launch_bounds__(256, 2) void gemm_q_kernel(
    const short* __restrict__ xb, const int* __restrict__ wq,
    const float* __restrict__ wsc, float* __restrict__ outp) {
  __shared__ short lA[2][BM * BK];
  __shared__ short lB[2][BN * BK];

  // XCD-aware swizzle: XCD x gets contiguous (nt,kh,mt) chunk -> 4 mt blocks
  // share each weight tile in that XCD's L2.
  const int b = blockIdx.x;
  int mt, nt, kh;
  if constexpr (SPLIT) {
    const int s = ((b & 7) << 6) | (b >> 3);
    mt = s & 3; kh = (s >> 2) & 1; nt = s >> 3;
  } else {
    const int s = ((b & 7) << 5) | (b >> 3);
    mt = s & 3; kh = 0; nt = s >> 2;
  }
  const int m0 = mt * BM;
  const int n0 = nt * BN;
  const int nkt = SPLIT ? 64 : 128;
  const int kbase = SPLIT ? kh * 4096 : 0;
  const int sbase = nt * 64 + (SPLIT ? kh * 32 : 0);

  const int t = threadIdx.x;
  const int w = t >> 6;
  const int l = t & 63;
  const int wm = (w >> 1) * 64;
  const int wn = (w & 1) * 64;

  // B staging: row = p*32 + urow, 8 ints at k-unit cu
  const int urow = t >> 3;
  const int cu = t & 7;
  // A staging: row = t>>1, k-units aq..aq+3
  const int arow = t >> 1;
  const int aq = (t & 1) * 4;

  v4f acc[4][4] = {};
  v4i breg[2][4][2];  // [set][p][half]
  v4i areg[2][4];     // [set][j]

  auto issue = [&](int ktl, int s) {
    const int* gB = wq + (size_t)n0 * KDIM + kbase + ktl * 64;
#pragma unroll
    for (int p = 0; p < 4; ++p) {
      const int* gp = gB + (size_t)(p * 32 + urow) * KDIM + cu * 8;
      breg[s][p][0] = *(const v4i*)gp;
      breg[s][p][1] = *(const v4i*)(gp + 4);
    }
    const int ktg = (SPLIT ? kh * 64 : 0) + ktl;
    const short* gA = xb + ((size_t)(mt * 128 + ktg) * 1024) * 8;
#pragma unroll
    for (int j = 0; j < 4; ++j)
      areg[s][j] = *(const v4i*)(gA + (size_t)(j * 256 + t) * 8);
  };

  auto write_stage = [&](int s, int buf, float sc) {
#pragma unroll
    for (int p = 0; p < 4; ++p) {
      v4i o;
      o[0] = pack_bf2(sc * (float)breg[s][p][0][0], sc * (float)breg[s][p][0][1]);
      o[1] = pack_bf2(sc * (float)breg[s][p][0][2], sc * (float)breg[s][p][0][3]);
      o[2] = pack_bf2(sc * (float)breg[s][p][1][0], sc * (float)breg[s][p][1][1]);
      o[3] = pack_bf2(sc * (float)breg[s][p][1][2], sc * (float)breg[s][p][1][3]);
      const int row = p * 32 + urow;
      *(v4i*)&lB[buf][row * BK + ((cu ^ (row & 7)) << 3)] = o;
    }
#pragma unroll
    for (int j = 0; j < 4; ++j)
      *(v4i*)&lA[buf][arow * BK + (((aq + j) ^ (arow & 7)) << 3)] = areg[s][j];
  };

  auto compute = [&](int buf) {
#pragma unroll
    for (int kk = 0; kk < 2; ++kk) {
      const int q = kk * 4 + (l >> 4);  // k-unit 0..7
      v8s af[4], bq[4];
#pragma unroll
      for (int i = 0; i < 4; ++i) {
        const int ra = wm + i * 16 + (l & 15);
        af[i] = *(const v8s*)&lA[buf][ra * BK + ((q ^ (ra & 7)) << 3)];
        const int rb = wn + i * 16 + (l & 15);
        bq[i] = *(const v8s*)&lB[buf][rb * BK + ((q ^ (rb & 7)) << 3)];
      }
#pragma unroll
      for (int i = 0; i < 4; ++i)
#pragma unroll
        for (int j = 0; j < 4; ++j)
          acc[i][j] = __builtin_amdgcn_mfma_f32_16x16x32_bf16(
              af[i], bq[j], acc[i][j], 0, 0, 0);
    }
  };

  // prologue: tiles 0 and 1 in flight; stage tile 0 into buf 0
  issue(0, 0);
  issue(1, 1);
  write_stage(0, 0, wsc[sbase]);  // compiler emits counted vmcnt for set 0
  block_sync();

  for (int ktl = 0; ktl < nkt; ++ktl) {
    const int cur = ktl & 1;
    if (ktl + 2 < nkt) issue(ktl + 2, cur);       // into set just freed
    compute(cur);                                  // MFMA on buf[cur]
    if (ktl + 1 < nkt)                             // counted vmcnt (never 0)
      write_stage((ktl + 1) & 1, cur ^ 1, wsc[sbase + ((ktl + 1) >> 1)]);
    block_sync();                                  // NO vmcnt drain
  }

  float* dst = outp + (SPLIT ? (size_t)kh * MDIM * NDIM : 0);
#pragma unroll
  for (int i = 0; i < 4; ++i) {
#pragma unroll
    for (int j = 0; j < 4; ++j) {
      const int mrow = m0 + wm + i * 16 + (l >> 4) * 4;
      const int ocol = n0 + wn + j * 16 + (l & 15);
#pragma unroll
      for (int r = 0; r < 4; ++r)
        dst[(size_t)(mrow + r) * NDIM + ocol] = acc[i][j][r];
    }
  }
}

extern "C" void kernel_launch(void* const* d_in, const int* in_sizes, int n_in,
                              void* d_out, int out_size, void* d_ws,
                              size_t ws_size, hipStream_t stream) {
  const float* x = (const float*)d_in[0];
  const int* wq = (const int*)d_in[1];
  const float* wsc = (const float*)d_in[2];
  float* out = (float*)d_out;

  const size_t xb_bytes = (size_t)MDIM * KDIM * sizeof(short);        // 8 MB
  const size_t part_bytes = (size_t)2 * MDIM * NDIM * sizeof(float);  // 32 MB

  short* xb = (short*)d_ws;
  cvt_x_kernel<<<dim3((MDIM * KDIM) / (256 * 8)), dim3(256), 0, stream>>>(x, xb);
  if (ws_size >= xb_bytes + part_bytes) {
    float* part = (float*)((char*)d_ws + xb_bytes);
    gemm_q_kernel<true><<<dim3(512), dim3(256), 0, stream>>>(xb, wq, wsc, part);
    reduce_kernel<<<dim3((MDIM * NDIM) / (256 * 4)), dim3(256), 0, stream>>>(part, out);
  } else {
    gemm_q_kernel<false><<<dim3(256), dim3(256), 0, stream>>>(xb, wq, wsc, out);
  }
}

// Round 4
// 145.526 us; speedup vs baseline: 3.4879x; 3.4879x over previous
//
#include <hip/hip_runtime.h>

#define MDIM 512
#define NDIM 8192
#define KDIM 8192
#define BM 128
#define BN 128
#define BK 64

typedef short v8s __attribute__((ext_vector_type(8)));
typedef float v4f __attribute__((ext_vector_type(4)));
typedef int   v4i __attribute__((ext_vector_type(4)));

// pack two f32 into two bf16 by truncation (high halves) via byte-perm
__device__ __forceinline__ unsigned pack_bf2(float a, float b) {
  unsigned ia = __builtin_bit_cast(unsigned, a);
  unsigned ib = __builtin_bit_cast(unsigned, b);
  return __builtin_amdgcn_perm(ib, ia, 0x07060302u);  // lo16=a.hi, hi16=b.hi
}

// round-to-nearest-ish (+0x8000 before truncation); inputs finite
__device__ __forceinline__ unsigned pack_bf2_rnd(float a, float b) {
  unsigned ia = __builtin_bit_cast(unsigned, a) + 0x8000u;
  unsigned ib = __builtin_bit_cast(unsigned, b) + 0x8000u;
  return __builtin_amdgcn_perm(ib, ia, 0x07060302u);
}

// Raw barrier WITHOUT vmcnt drain: in-flight global loads stay outstanding
// across it. lgkmcnt(0) publishes ds_writes (and retires ds_reads);
// sched_barrier fences stop code motion across it (rule 18).
__device__ __forceinline__ void block_sync() {
  asm volatile("s_waitcnt lgkmcnt(0)" ::: "memory");
  __builtin_amdgcn_sched_barrier(0);
  __builtin_amdgcn_s_barrier();
  __builtin_amdgcn_sched_barrier(0);
}

// x fp32 -> bf16, tiled [4 mt][128 ktg][1024 units]*8elem, unit position
// pos = (u&3)*256 + (u>>2) so the gemm's 4 per-thread loads are each
// lane-dense (16B * 64 lanes contiguous). u: row=u>>3 (0..127), q=u&7.
__global__ __launch_bounds__(256) void cvt_x_kernel(const float* __restrict__ x,
                                                    short* __restrict__ xb) {
  const int g = blockIdx.x * 256 + threadIdx.x;  // global unit position
  const int mt = g >> 17;
  const int rem = g & 131071;
  const int ktg = rem >> 10;
  const int upos = rem & 1023;
  const int u = (upos & 255) * 4 + (upos >> 8);  // invert pos()
  const int row = u >> 3;
  const int q = u & 7;
  const float* src = x + (size_t)(mt * BM + row) * KDIM + ktg * BK + q * 8;
  v4f f0 = *(const v4f*)src;
  v4f f1 = *(const v4f*)(src + 4);
  v4i o;
  o[0] = pack_bf2_rnd(f0[0], f0[1]);
  o[1] = pack_bf2_rnd(f0[2], f0[3]);
  o[2] = pack_bf2_rnd(f1[0], f1[1]);
  o[3] = pack_bf2_rnd(f1[2], f1[3]);
  *(v4i*)(xb + (size_t)g * 8) = o;
}

// out[i] = p0[i] + p1[i]  (split-K reduction, deterministic)
__global__ __launch_bounds__(256) void reduce_kernel(const float* __restrict__ p,
                                                     float* __restrict__ out) {
  const size_t i = ((size_t)blockIdx.x * 256 + threadIdx.x) * 4;
  v4f a = *(const v4f*)(p + i);
  v4f b = *(const v4f*)(p + (size_t)MDIM * NDIM + i);
  *(v4f*)(out + i) = a + b;
}

// Fused dequant GEMM, depth-2 register pipeline (two NAMED register sets,
// all indices compile-time -> no scratch, rule #20) + raw counted barriers.
// SPLIT: 2-way split-K (grid 512, partials), else grid 256 direct.
template <bool SPLIT>
__global__ __launch_bounds__(256, 2) void gemm_q_kernel(
    const short* __restrict__ xb, const int* __restrict__ wq,
    const float* __restrict__ wsc, float* __restrict__ outp) {
  __shared__ short lA[2][BM * BK];
  __shared__ short lB[2][BN * BK];

  // XCD-aware swizzle: XCD x gets contiguous (nt,kh,mt) chunk -> 4 mt blocks
  // share each weight tile in that XCD's L2.
  const int b = blockIdx.x;
  int mt, nt, kh;
  if constexpr (SPLIT) {
    const int s = ((b & 7) << 6) | (b >> 3);
    mt = s & 3; kh = (s >> 2) & 1; nt = s >> 3;
  } else {
    const int s = ((b & 7) << 5) | (b >> 3);
    mt = s & 3; kh = 0; nt = s >> 2;
  }
  const int m0 = mt * BM;
  const int n0 = nt * BN;
  const int nkt = SPLIT ? 64 : 128;  // even
  const int kbase = SPLIT ? kh * 4096 : 0;
  const int sbase = nt * 64 + (SPLIT ? kh * 32 : 0);

  const int t = threadIdx.x;
  const int w = t >> 6;
  const int l = t & 63;
  const int wm = (w >> 1) * 64;
  const int wn = (w & 1) * 64;

  // B staging: row = p*32 + urow, 8 ints at k-unit cu
  const int urow = t >> 3;
  const int cu = t & 7;
  // A staging: row = t>>1, k-units aq..aq+3
  const int arow = t >> 1;
  const int aq = (t & 1) * 4;

  v4f acc[4][4] = {};
  v4i b0[4][2], b1[4][2];  // named sets — compile-time indexed only
  v4i a0[4], a1[4];

  auto issue = [&](int ktl, v4i (&br)[4][2], v4i (&ar)[4]) {
    const int* gB = wq + (size_t)n0 * KDIM + kbase + ktl * 64;
#pragma unroll
    for (int p = 0; p < 4; ++p) {
      const int* gp = gB + (size_t)(p * 32 + urow) * KDIM + cu * 8;
      br[p][0] = *(const v4i*)gp;
      br[p][1] = *(const v4i*)(gp + 4);
    }
    const int ktg = (SPLIT ? kh * 64 : 0) + ktl;
    const short* gA = xb + (size_t)(mt * 128 + ktg) * 8192;
#pragma unroll
    for (int j = 0; j < 4; ++j)
      ar[j] = *(const v4i*)(gA + (size_t)(j * 256 + t) * 8);
  };

  auto stage = [&](v4i (&br)[4][2], v4i (&ar)[4], int buf, float sc) {
#pragma unroll
    for (int p = 0; p < 4; ++p) {
      v4i o;
      o[0] = pack_bf2(sc * (float)br[p][0][0], sc * (float)br[p][0][1]);
      o[1] = pack_bf2(sc * (float)br[p][0][2], sc * (float)br[p][0][3]);
      o[2] = pack_bf2(sc * (float)br[p][1][0], sc * (float)br[p][1][1]);
      o[3] = pack_bf2(sc * (float)br[p][1][2], sc * (float)br[p][1][3]);
      const int row = p * 32 + urow;
      *(v4i*)&lB[buf][row * BK + ((cu ^ (row & 7)) << 3)] = o;
    }
#pragma unroll
    for (int j = 0; j < 4; ++j)
      *(v4i*)&lA[buf][arow * BK + (((aq + j) ^ (arow & 7)) << 3)] = ar[j];
  };

  auto compute = [&](int buf) {
#pragma unroll
    for (int kk = 0; kk < 2; ++kk) {
      const int q = kk * 4 + (l >> 4);  // k-unit 0..7
      v8s af[4], bq[4];
#pragma unroll
      for (int i = 0; i < 4; ++i) {
        const int ra = wm + i * 16 + (l & 15);
        af[i] = *(const v8s*)&lA[buf][ra * BK + ((q ^ (ra & 7)) << 3)];
        const int rb = wn + i * 16 + (l & 15);
        bq[i] = *(const v8s*)&lB[buf][rb * BK + ((q ^ (rb & 7)) << 3)];
      }
#pragma unroll
      for (int i = 0; i < 4; ++i)
#pragma unroll
        for (int j = 0; j < 4; ++j)
          acc[i][j] = __builtin_amdgcn_mfma_f32_16x16x32_bf16(
              af[i], bq[j], acc[i][j], 0, 0, 0);
    }
  };

  // prologue: tiles 0,1 in flight; stage tile 0 (compiler emits counted
  // vmcnt(8A+..) wait for set0 only — set1's 12 loads stay outstanding)
  issue(0, b0, a0);
  issue(1, b1, a1);
  stage(b0, a0, 0, wsc[sbase]);
  block_sync();

#pragma unroll 1
  for (int kt = 0; kt < nkt; kt += 2) {
    // phase 0: compute tile kt from buf0; set0 regs are free
    if (kt + 2 < nkt) issue(kt + 2, b0, a0);
    compute(0);
    stage(b1, a1, 1, wsc[sbase + ((kt + 1) >> 1)]);  // tile kt+1 -> buf1
    block_sync();
    // phase 1: compute tile kt+1 from buf1; set1 regs are free
    if (kt + 3 < nkt) issue(kt + 3, b1, a1);
    compute(1);
    if (kt + 2 < nkt) stage(b0, a0, 0, wsc[sbase + ((kt + 2) >> 1)]);
    block_sync();
  }

  float* dst = outp + (SPLIT ? (size_t)kh * MDIM * NDIM : 0);
#pragma unroll
  for (int i = 0; i < 4; ++i) {
#pragma unroll
    for (int j = 0; j < 4; ++j) {
      const int mrow = m0 + wm + i * 16 + (l >> 4) * 4;
      const int ocol = n0 + wn + j * 16 + (l & 15);
#pragma unroll
      for (int r = 0; r < 4; ++r)
        dst[(size_t)(mrow + r) * NDIM + ocol] = acc[i][j][r];
    }
  }
}

extern "C" void kernel_launch(void* const* d_in, const int* in_sizes, int n_in,
                              void* d_out, int out_size, void* d_ws,
                              size_t ws_size, hipStream_t stream) {
  const float* x = (const float*)d_in[0];
  const int* wq = (const int*)d_in[1];
  const float* wsc = (const float*)d_in[2];
  float* out = (float*)d_out;

  const size_t xb_bytes = (size_t)MDIM * KDIM * sizeof(short);        // 8 MB
  const size_t part_bytes = (size_t)2 * MDIM * NDIM * sizeof(float);  // 32 MB

  short* xb = (short*)d_ws;
  cvt_x_kernel<<<dim3((MDIM * KDIM) / (256 * 8)), dim3(256), 0, stream>>>(x, xb);
  if (ws_size >= xb_bytes + part_bytes) {
    float* part = (float*)((char*)d_ws + xb_bytes);
    gemm_q_kernel<true><<<dim3(512), dim3(256), 0, stream>>>(xb, wq, wsc, part);
    reduce_kernel<<<dim3((MDIM * NDIM) / (256 * 4)), dim3(256), 0, stream>>>(part, out);
  } else {
    gemm_q_kernel<false><<<dim3(256), dim3(256), 0, stream>>>(xb, wq, wsc, out);
  }
}